// Round 4
// baseline (5047.971 us; speedup 1.0000x reference)
//
#include <hip/hip_runtime.h>
#include <math.h>

// Problem constants (z: [2,16384,256] f32, emb: [8192,256] f32)
#define D_DIM 256
#define NE    8192
#define M_TOT 32768L

// Output layout (f32 elements): z_q_st | loss | idx | age | usage
#define O_LOSS  8388608L
#define O_IDX   8388609L
#define O_AGE   8421377L
#define O_USAGE 8429569L

// ws layout: zzf[32768] f32 | enf[8192] f32 | idx_ws[32768] i32 | cnt i32 |
//            flagged[32768] i32   (~416 KB)

// ---------------------------------------------------------------------------
// Kernel 1: f32 row norms (f64-accumulated, f32-rounded) for z and emb,
// init age/usage defaults, zero loss + flag counter.
__global__ __launch_bounds__(256) void vq_prep(
    const float* __restrict__ z, const float* __restrict__ emb,
    const float* __restrict__ code_age, const float* __restrict__ code_usage,
    float* __restrict__ out, float* __restrict__ zzf, float* __restrict__ enf,
    int* __restrict__ cnt) {
  int t = blockIdx.x * 256 + threadIdx.x;  // 0..32767
  {
    const float4* row = reinterpret_cast<const float4*>(z + (size_t)t * D_DIM);
    double s = 0.0;
#pragma unroll
    for (int q = 0; q < D_DIM / 4; ++q) {
      float4 v = row[q];
      s = fma((double)v.x, (double)v.x, s);
      s = fma((double)v.y, (double)v.y, s);
      s = fma((double)v.z, (double)v.z, s);
      s = fma((double)v.w, (double)v.w, s);
    }
    zzf[t] = (float)s;
  }
  if (t < NE) {
    const float4* row = reinterpret_cast<const float4*>(emb + (size_t)t * D_DIM);
    double s = 0.0;
#pragma unroll
    for (int q = 0; q < D_DIM / 4; ++q) {
      float4 v = row[q];
      s = fma((double)v.x, (double)v.x, s);
      s = fma((double)v.y, (double)v.y, s);
      s = fma((double)v.z, (double)v.z, s);
      s = fma((double)v.w, (double)v.w, s);
    }
    enf[t] = (float)s;
    out[O_AGE + t] = code_age[t] + 1.0f;
    out[O_USAGE + t] = code_usage[t];
    if (t == 0) { out[O_LOSS] = 0.0f; *cnt = 0; }
  }
}

// ---------------------------------------------------------------------------
// Kernel 2: f32 GEMM pass. 128x128 tile, BK=32, 256 threads, 8x8 acc/thread.
// Epilogue applies the reference's f32 chain dv = fl(fl(zz-2*ze)+en), keeps
// per-row top-2; rows with (v2-v1) <= margin are flagged for exact refine.
#define BM 128
#define BN 128
#define BK 32
#define LDP 132

__global__ __launch_bounds__(256) void vq_argmin_f32(
    const float* __restrict__ z, const float* __restrict__ emb,
    const float* __restrict__ zzf, const float* __restrict__ enf,
    int* __restrict__ idx_ws, int* __restrict__ cnt, int* __restrict__ flagged) {
  __shared__ float As[BK][LDP];   // As[k][row]
  __shared__ float Bs[BK][LDP];   // Bs[k][code]

  const int tid = threadIdx.x;
  const int tx = tid & 15, ty = tid >> 4;
  const size_t row0 = (size_t)blockIdx.x * BM;

  const int lr = tid >> 1;          // staging: row/code 0..127
  const int lk = (tid & 1) * 16;    // k offset 0 or 16

  float zrow2[8];
#pragma unroll
  for (int i = 0; i < 8; ++i) zrow2[i] = zzf[row0 + ty * 8 + i];

  float bv1[8], bv2[8];
  int bj1[8];
#pragma unroll
  for (int i = 0; i < 8; ++i) { bv1[i] = INFINITY; bv2[i] = INFINITY; bj1[i] = 0; }

  for (int jt = 0; jt < NE; jt += BN) {
    float acc[8][8];
#pragma unroll
    for (int i = 0; i < 8; ++i)
#pragma unroll
      for (int j = 0; j < 8; ++j) acc[i][j] = 0.f;

    for (int k0 = 0; k0 < D_DIM; k0 += BK) {
      __syncthreads();
#pragma unroll
      for (int q = 0; q < 4; ++q) {
        float4 av = *reinterpret_cast<const float4*>(
            z + (row0 + lr) * (size_t)D_DIM + k0 + lk + q * 4);
        As[lk + q * 4 + 0][lr] = av.x; As[lk + q * 4 + 1][lr] = av.y;
        As[lk + q * 4 + 2][lr] = av.z; As[lk + q * 4 + 3][lr] = av.w;
        float4 ev = *reinterpret_cast<const float4*>(
            emb + (size_t)(jt + lr) * D_DIM + k0 + lk + q * 4);
        Bs[lk + q * 4 + 0][lr] = ev.x; Bs[lk + q * 4 + 1][lr] = ev.y;
        Bs[lk + q * 4 + 2][lr] = ev.z; Bs[lk + q * 4 + 3][lr] = ev.w;
      }
      __syncthreads();
#pragma unroll 4
      for (int k = 0; k < BK; ++k) {
        float a[8], b[8];
        *reinterpret_cast<float4*>(&a[0]) = *reinterpret_cast<const float4*>(&As[k][ty * 8]);
        *reinterpret_cast<float4*>(&a[4]) = *reinterpret_cast<const float4*>(&As[k][ty * 8 + 4]);
        *reinterpret_cast<float4*>(&b[0]) = *reinterpret_cast<const float4*>(&Bs[k][tx * 8]);
        *reinterpret_cast<float4*>(&b[4]) = *reinterpret_cast<const float4*>(&Bs[k][tx * 8 + 4]);
#pragma unroll
        for (int i = 0; i < 8; ++i)
#pragma unroll
          for (int j = 0; j < 8; ++j)
            acc[i][j] = fmaf(a[i], b[j], acc[i][j]);
      }
    }
    // epilogue: reference f32 chain; ascending gj + strict < -> lowest index
#pragma unroll
    for (int j = 0; j < 8; ++j) {
      int gj = jt + tx * 8 + j;
      float ef = enf[gj];
#pragma unroll
      for (int i = 0; i < 8; ++i) {
        float t = zrow2[i] - 2.0f * acc[i][j];
        float dv = t + ef;
        if (dv < bv1[i]) {
          bv2[i] = bv1[i]; bv1[i] = dv; bj1[i] = gj;
        } else if (dv < bv2[i]) {
          bv2[i] = dv;
        }
      }
    }
  }

  // merge top-2 across the 16 tx lanes of each ty group (within-wave groups)
#pragma unroll
  for (int m = 1; m < 16; m <<= 1) {
#pragma unroll
    for (int i = 0; i < 8; ++i) {
      float ov1 = __shfl_xor(bv1[i], m, 16);
      float ov2 = __shfl_xor(bv2[i], m, 16);
      int oj1 = __shfl_xor(bj1[i], m, 16);
      if (ov1 < bv1[i] || (ov1 == bv1[i] && oj1 < bj1[i])) {
        bv2[i] = fminf(bv1[i], ov2);
        bv1[i] = ov1; bj1[i] = oj1;
      } else {
        bv2[i] = fminf(bv2[i], ov1);
      }
    }
  }
  if (tx == 0) {
#pragma unroll
    for (int i = 0; i < 8; ++i) {
      size_t grow = row0 + (size_t)ty * 8 + i;
      idx_ws[grow] = bj1[i];
      // margin: 3*ulp(dv scale) + slack; dv binade == zz binade (2ze,en tiny)
      float uz = ldexpf(1.0f, ilogbf(zrow2[i]) - 23);
      if (bv2[i] - bv1[i] <= 3.0f * uz + 1e-6f) {
        int p = atomicAdd(cnt, 1);
        flagged[p] = (int)grow;
      }
    }
  }
}

// ---------------------------------------------------------------------------
// Kernel 3: exact refine for flagged rows. 8 rows per block, full 8192-code
// scan, f64 dot, reference f32 quantization chain, lowest-index ties.
#define RROWS 8

__global__ __launch_bounds__(256) void vq_refine(
    const float* __restrict__ z, const float* __restrict__ emb,
    const float* __restrict__ zzf, const float* __restrict__ enf,
    int* __restrict__ idx_ws, const int* __restrict__ cnt,
    const int* __restrict__ flagged) {
  __shared__ float zs[RROWS][D_DIM + 4];
  __shared__ float rzz[RROWS];
  __shared__ float rv[RROWS][256];
  __shared__ int rj[RROWS][256];

  const int tid = threadIdx.x;
  int n = *cnt;
  if (n > (int)M_TOT) n = (int)M_TOT;

  for (int base = blockIdx.x * RROWS; base < n; base += gridDim.x * RROWS) {
    int nb = n - base; if (nb > RROWS) nb = RROWS;
    __syncthreads();
    {
      int r = tid >> 5;               // 8 rows x 32 threads
      int kk = (tid & 31) * 8;        // 8 floats each
      if (r < nb) {
        size_t m = (size_t)flagged[base + r];
        *reinterpret_cast<float4*>(&zs[r][kk]) =
            *reinterpret_cast<const float4*>(z + m * D_DIM + kk);
        *reinterpret_cast<float4*>(&zs[r][kk + 4]) =
            *reinterpret_cast<const float4*>(z + m * D_DIM + kk + 4);
      }
      if (tid < nb) rzz[tid] = zzf[flagged[base + tid]];
    }
    __syncthreads();

    float bv[RROWS]; int bj[RROWS];
#pragma unroll
    for (int r = 0; r < RROWS; ++r) { bv[r] = INFINITY; bj[r] = 0; }

    for (int j = tid; j < NE; j += 256) {
      const float4* er = reinterpret_cast<const float4*>(emb + (size_t)j * D_DIM);
      double acc[RROWS];
#pragma unroll
      for (int r = 0; r < RROWS; ++r) acc[r] = 0.0;
      for (int k4 = 0; k4 < D_DIM / 4; ++k4) {
        float4 ev = er[k4];
        double e0 = ev.x, e1 = ev.y, e2 = ev.z, e3 = ev.w;
#pragma unroll
        for (int r = 0; r < RROWS; ++r) {
          float4 zv = *reinterpret_cast<const float4*>(&zs[r][k4 * 4]);
          double a = acc[r];
          a = fma((double)zv.x, e0, a);
          a = fma((double)zv.y, e1, a);
          a = fma((double)zv.z, e2, a);
          a = fma((double)zv.w, e3, a);
          acc[r] = a;
        }
      }
      float ef = enf[j];
#pragma unroll
      for (int r = 0; r < RROWS; ++r) {
        float zef = (float)acc[r];          // correctly-rounded f32(ze)
        float t = rzz[r] - 2.0f * zef;
        float dv = t + ef;
        if (dv < bv[r]) { bv[r] = dv; bj[r] = j; }   // j ascending
      }
    }
#pragma unroll
    for (int r = 0; r < RROWS; ++r) { rv[r][tid] = bv[r]; rj[r][tid] = bj[r]; }
    __syncthreads();
    for (int s = 128; s > 0; s >>= 1) {
      if (tid < s) {
#pragma unroll
        for (int r = 0; r < RROWS; ++r) {
          float ov = rv[r][tid + s]; int oj = rj[r][tid + s];
          if (ov < rv[r][tid] || (ov == rv[r][tid] && oj < rj[r][tid])) {
            rv[r][tid] = ov; rj[r][tid] = oj;
          }
        }
      }
      __syncthreads();
    }
    if (tid < nb) idx_ws[flagged[base + tid]] = rj[tid][0];
  }
}

// ---------------------------------------------------------------------------
// Kernel 4: idx (as float), age reset, usage histogram — after refine.
__global__ __launch_bounds__(256) void vq_scatter(
    const int* __restrict__ idx_ws, float* __restrict__ out) {
  int m = blockIdx.x * 256 + threadIdx.x;
  if (m >= M_TOT) return;
  int j = idx_ws[m];
  out[O_IDX + m] = (float)j;
  out[O_AGE + j] = 0.0f;            // benign race: all write 0
  atomicAdd(&out[O_USAGE + j], 1.0f);
}

// ---------------------------------------------------------------------------
// Kernel 5: z_q_st = z + (q - z) (mimics ref rounding), loss accumulation.
__global__ __launch_bounds__(256) void vq_gather(
    const float* __restrict__ z, const float* __restrict__ emb,
    const int* __restrict__ idx_ws, float* __restrict__ out) {
  size_t e4 = (size_t)blockIdx.x * 256 + threadIdx.x;  // float4 index
  size_t m = e4 >> 6;       // / (D/4)
  int dq = (int)(e4 & 63);
  int j = idx_ws[m];
  float4 q = *reinterpret_cast<const float4*>(emb + (size_t)j * D_DIM + dq * 4);
  float4 zv = *reinterpret_cast<const float4*>(z + e4 * 4);
  float dx = q.x - zv.x, dy = q.y - zv.y, dz = q.z - zv.z, dw = q.w - zv.w;
  float4 o;
  o.x = zv.x + dx; o.y = zv.y + dy; o.z = zv.z + dz; o.w = zv.w + dw;
  *reinterpret_cast<float4*>(out + e4 * 4) = o;
  float ls = dx * dx + dy * dy + dz * dz + dw * dw;
#pragma unroll
  for (int off = 32; off > 0; off >>= 1) ls += __shfl_down(ls, off, 64);
  if ((threadIdx.x & 63) == 0)
    atomicAdd(out + O_LOSS, ls * (1.25f / 8388608.f));  // (1+beta)/(M*D)
}

// ---------------------------------------------------------------------------
extern "C" void kernel_launch(void* const* d_in, const int* in_sizes, int n_in,
                              void* d_out, int out_size, void* d_ws, size_t ws_size,
                              hipStream_t stream) {
  const float* z = (const float*)d_in[0];
  const float* emb = (const float*)d_in[1];
  const float* code_age = (const float*)d_in[2];
  const float* code_usage = (const float*)d_in[3];
  float* out = (float*)d_out;

  float* zzf = (float*)d_ws;
  float* enf = zzf + M_TOT;
  int* idx_ws = (int*)(enf + NE);
  int* cnt = idx_ws + M_TOT;
  int* flagged = cnt + 1;

  hipLaunchKernelGGL(vq_prep, dim3(M_TOT / 256), dim3(256), 0, stream,
                     z, emb, code_age, code_usage, out, zzf, enf, cnt);
  hipLaunchKernelGGL(vq_argmin_f32, dim3(M_TOT / BM), dim3(256), 0, stream,
                     z, emb, zzf, enf, idx_ws, cnt, flagged);
  hipLaunchKernelGGL(vq_refine, dim3(512), dim3(256), 0, stream,
                     z, emb, zzf, enf, idx_ws, cnt, flagged);
  hipLaunchKernelGGL(vq_scatter, dim3(M_TOT / 256), dim3(256), 0, stream,
                     idx_ws, out);
  hipLaunchKernelGGL(vq_gather, dim3((M_TOT * (D_DIM / 4)) / 256), dim3(256), 0, stream,
                     z, emb, idx_ws, out);
}

// Round 5
// 3120.070 us; speedup vs baseline: 1.6179x; 1.6179x over previous
//
#include <hip/hip_runtime.h>
#include <math.h>

// Problem constants (z: [2,16384,256] f32, emb: [8192,256] f32)
#define D_DIM 256
#define NE    8192
#define M_TOT 32768L

// Output layout (f32 elements): z_q_st | loss | idx | age | usage
#define O_LOSS  8388608L
#define O_IDX   8388609L
#define O_AGE   8421377L
#define O_USAGE 8429569L

// ---------------------------------------------------------------------------
// Kernel 1: f32 row norms (f64-accumulated, f32-rounded) for z and emb,
// init age/usage defaults, zero loss + flag counter.
__global__ __launch_bounds__(256) void vq_prep(
    const float* __restrict__ z, const float* __restrict__ emb,
    const float* __restrict__ code_age, const float* __restrict__ code_usage,
    float* __restrict__ out, float* __restrict__ zzf, float* __restrict__ enf,
    int* __restrict__ cnt) {
  int t = blockIdx.x * 256 + threadIdx.x;  // 0..32767
  {
    const float4* row = reinterpret_cast<const float4*>(z + (size_t)t * D_DIM);
    double s = 0.0;
#pragma unroll
    for (int q = 0; q < D_DIM / 4; ++q) {
      float4 v = row[q];
      s = fma((double)v.x, (double)v.x, s);
      s = fma((double)v.y, (double)v.y, s);
      s = fma((double)v.z, (double)v.z, s);
      s = fma((double)v.w, (double)v.w, s);
    }
    zzf[t] = (float)s;
  }
  if (t < NE) {
    const float4* row = reinterpret_cast<const float4*>(emb + (size_t)t * D_DIM);
    double s = 0.0;
#pragma unroll
    for (int q = 0; q < D_DIM / 4; ++q) {
      float4 v = row[q];
      s = fma((double)v.x, (double)v.x, s);
      s = fma((double)v.y, (double)v.y, s);
      s = fma((double)v.z, (double)v.z, s);
      s = fma((double)v.w, (double)v.w, s);
    }
    enf[t] = (float)s;
    out[O_AGE + t] = code_age[t] + 1.0f;
    out[O_USAGE + t] = code_usage[t];
    if (t == 0) { out[O_LOSS] = 0.0f; *cnt = 0; }
  }
}

// ---------------------------------------------------------------------------
// Kernel 2: f32 GEMM pass, code-split x4 for occupancy (1024 blocks = 4/CU).
// 128 rows x 2048 codes per block (16 tiles of 128), BK=32, 8x8 acc/thread.
// Per-row top-2 partials written to ws; merge kernel folds splits.
#define BM 128
#define BN 128
#define BK 32
#define NSPLIT 4
#define JTILES (NE / NSPLIT / BN)   // 16
#define LDA 132
#define LDB 144   // swizzled: code c -> col c + ((c>>5)&3)*4  (2-way banks)

__global__ __launch_bounds__(256, 1) void vq_argmin_f32(
    const float* __restrict__ z, const float* __restrict__ emb,
    const float* __restrict__ zzf, const float* __restrict__ enf,
    float* __restrict__ pv1, float* __restrict__ pv2, int* __restrict__ pj1) {
  __shared__ float As[BK][LDA];   // As[k][row]
  __shared__ float Bs[BK][LDB];   // Bs[k][swizzled code col]

  const int tid = threadIdx.x;
  const int tx = tid & 15, ty = tid >> 4;
  const size_t row0 = (size_t)blockIdx.x * BM;
  const int jbase = blockIdx.y * (NE / NSPLIT);

  const int lr = tid >> 1;          // staging: row/code 0..127
  const int lk = (tid & 1) * 16;    // k offset 0 or 16
  const int wcol = lr + (((lr >> 5) & 3) << 2);           // B staging col
  const int brd = tx * 8 + (((tx >> 2) & 3) << 2);        // B read col base

  float zrow2[8];
#pragma unroll
  for (int i = 0; i < 8; ++i) zrow2[i] = zzf[row0 + ty * 8 + i];

  float bv1[8], bv2[8];
  int bj1[8];
#pragma unroll
  for (int i = 0; i < 8; ++i) { bv1[i] = INFINITY; bv2[i] = INFINITY; bj1[i] = 0; }

  for (int jt = 0; jt < JTILES; ++jt) {
    const int jt0 = jbase + jt * BN;
    float acc[8][8];
#pragma unroll
    for (int i = 0; i < 8; ++i)
#pragma unroll
      for (int j = 0; j < 8; ++j) acc[i][j] = 0.f;

    for (int k0 = 0; k0 < D_DIM; k0 += BK) {
      __syncthreads();
#pragma unroll
      for (int q = 0; q < 4; ++q) {
        float4 av = *reinterpret_cast<const float4*>(
            z + (row0 + lr) * (size_t)D_DIM + k0 + lk + q * 4);
        As[lk + q * 4 + 0][lr] = av.x; As[lk + q * 4 + 1][lr] = av.y;
        As[lk + q * 4 + 2][lr] = av.z; As[lk + q * 4 + 3][lr] = av.w;
        float4 ev = *reinterpret_cast<const float4*>(
            emb + (size_t)(jt0 + lr) * D_DIM + k0 + lk + q * 4);
        Bs[lk + q * 4 + 0][wcol] = ev.x; Bs[lk + q * 4 + 1][wcol] = ev.y;
        Bs[lk + q * 4 + 2][wcol] = ev.z; Bs[lk + q * 4 + 3][wcol] = ev.w;
      }
      __syncthreads();
#pragma unroll 4
      for (int k = 0; k < BK; ++k) {
        float a[8], b[8];
        *reinterpret_cast<float4*>(&a[0]) = *reinterpret_cast<const float4*>(&As[k][ty * 8]);
        *reinterpret_cast<float4*>(&a[4]) = *reinterpret_cast<const float4*>(&As[k][ty * 8 + 4]);
        *reinterpret_cast<float4*>(&b[0]) = *reinterpret_cast<const float4*>(&Bs[k][brd]);
        *reinterpret_cast<float4*>(&b[4]) = *reinterpret_cast<const float4*>(&Bs[k][brd + 4]);
#pragma unroll
        for (int i = 0; i < 8; ++i)
#pragma unroll
          for (int j = 0; j < 8; ++j)
            acc[i][j] = fmaf(a[i], b[j], acc[i][j]);
      }
    }
    // epilogue: reference f32 chain; ascending gj + strict < -> lowest index
#pragma unroll
    for (int j = 0; j < 8; ++j) {
      int gj = jt0 + tx * 8 + j;
      float ef = enf[gj];
#pragma unroll
      for (int i = 0; i < 8; ++i) {
        float t = zrow2[i] - 2.0f * acc[i][j];
        float dv = t + ef;
        if (dv < bv1[i]) {
          bv2[i] = bv1[i]; bv1[i] = dv; bj1[i] = gj;
        } else if (dv < bv2[i]) {
          bv2[i] = dv;
        }
      }
    }
  }

  // merge top-2 across the 16 tx lanes of each ty group (within-wave)
#pragma unroll
  for (int m = 1; m < 16; m <<= 1) {
#pragma unroll
    for (int i = 0; i < 8; ++i) {
      float ov1 = __shfl_xor(bv1[i], m, 16);
      float ov2 = __shfl_xor(bv2[i], m, 16);
      int oj1 = __shfl_xor(bj1[i], m, 16);
      if (ov1 < bv1[i] || (ov1 == bv1[i] && oj1 < bj1[i])) {
        bv2[i] = fminf(bv1[i], ov2);
        bv1[i] = ov1; bj1[i] = oj1;
      } else {
        bv2[i] = fminf(bv2[i], ov1);
      }
    }
  }
  if (tx == 0) {
#pragma unroll
    for (int i = 0; i < 8; ++i) {
      size_t o = (size_t)blockIdx.y * M_TOT + row0 + (size_t)ty * 8 + i;
      pv1[o] = bv1[i]; pv2[o] = bv2[i]; pj1[o] = bj1[i];
    }
  }
}

// ---------------------------------------------------------------------------
// Kernel 3: fold the NSPLIT partial top-2s per row; flag ambiguous rows.
// Sufficient margin: unflagged gap > 2*ulp(v2) + slack  =>  ref argmin == ours
// (our dv differs from ref dv by at most one grid step; proof in notes).
__global__ __launch_bounds__(256) void vq_merge(
    const float* __restrict__ pv1, const float* __restrict__ pv2,
    const int* __restrict__ pj1, int* __restrict__ idx_ws,
    int* __restrict__ cnt, int* __restrict__ flagged) {
  int m = blockIdx.x * 256 + threadIdx.x;
  if (m >= M_TOT) return;
  float v1 = INFINITY, v2 = INFINITY;
  int j1 = 0;
#pragma unroll
  for (int s = 0; s < NSPLIT; ++s) {
    float a1 = pv1[(size_t)s * M_TOT + m];
    float a2 = pv2[(size_t)s * M_TOT + m];
    int aj = pj1[(size_t)s * M_TOT + m];
    if (a1 < v1 || (a1 == v1 && aj < j1)) {
      v2 = fminf(v1, a2); v1 = a1; j1 = aj;
    } else {
      v2 = fminf(v2, a1);
    }
  }
  idx_ws[m] = j1;
  float u = ldexpf(1.0f, ilogbf(v2) - 23);
  if (v2 - v1 <= 2.0f * u + 2e-7f) {
    int p = atomicAdd(cnt, 1);
    flagged[p] = m;
  }
}

// ---------------------------------------------------------------------------
// Kernel 4: exact refine for flagged rows. 8 rows per block, full 8192-code
// scan, f64 dot, reference f32 quantization chain, lowest-index ties.
#define RROWS 8

__global__ __launch_bounds__(256) void vq_refine(
    const float* __restrict__ z, const float* __restrict__ emb,
    const float* __restrict__ zzf, const float* __restrict__ enf,
    int* __restrict__ idx_ws, const int* __restrict__ cnt,
    const int* __restrict__ flagged) {
  __shared__ float zs[RROWS][D_DIM + 4];
  __shared__ float rzz[RROWS];
  __shared__ float rv[RROWS][256];
  __shared__ int rj[RROWS][256];

  const int tid = threadIdx.x;
  int n = *cnt;
  if (n > (int)M_TOT) n = (int)M_TOT;

  for (int base = blockIdx.x * RROWS; base < n; base += gridDim.x * RROWS) {
    int nb = n - base; if (nb > RROWS) nb = RROWS;
    __syncthreads();
    {
      int r = tid >> 5;               // 8 rows x 32 threads
      int kk = (tid & 31) * 8;        // 8 floats each
      if (r < nb) {
        size_t m = (size_t)flagged[base + r];
        *reinterpret_cast<float4*>(&zs[r][kk]) =
            *reinterpret_cast<const float4*>(z + m * D_DIM + kk);
        *reinterpret_cast<float4*>(&zs[r][kk + 4]) =
            *reinterpret_cast<const float4*>(z + m * D_DIM + kk + 4);
      }
      if (tid < nb) rzz[tid] = zzf[flagged[base + tid]];
    }
    __syncthreads();

    float bv[RROWS]; int bj[RROWS];
#pragma unroll
    for (int r = 0; r < RROWS; ++r) { bv[r] = INFINITY; bj[r] = 0; }

    for (int j = tid; j < NE; j += 256) {
      const float4* er = reinterpret_cast<const float4*>(emb + (size_t)j * D_DIM);
      double acc[RROWS];
#pragma unroll
      for (int r = 0; r < RROWS; ++r) acc[r] = 0.0;
      for (int k4 = 0; k4 < D_DIM / 4; ++k4) {
        float4 ev = er[k4];
        double e0 = ev.x, e1 = ev.y, e2 = ev.z, e3 = ev.w;
#pragma unroll
        for (int r = 0; r < RROWS; ++r) {
          float4 zv = *reinterpret_cast<const float4*>(&zs[r][k4 * 4]);
          double a = acc[r];
          a = fma((double)zv.x, e0, a);
          a = fma((double)zv.y, e1, a);
          a = fma((double)zv.z, e2, a);
          a = fma((double)zv.w, e3, a);
          acc[r] = a;
        }
      }
      float ef = enf[j];
#pragma unroll
      for (int r = 0; r < RROWS; ++r) {
        float zef = (float)acc[r];          // correctly-rounded f32(ze)
        float t = rzz[r] - 2.0f * zef;
        float dv = t + ef;
        if (dv < bv[r]) { bv[r] = dv; bj[r] = j; }   // j ascending
      }
    }
#pragma unroll
    for (int r = 0; r < RROWS; ++r) { rv[r][tid] = bv[r]; rj[r][tid] = bj[r]; }
    __syncthreads();
    for (int s = 128; s > 0; s >>= 1) {
      if (tid < s) {
#pragma unroll
        for (int r = 0; r < RROWS; ++r) {
          float ov = rv[r][tid + s]; int oj = rj[r][tid + s];
          if (ov < rv[r][tid] || (ov == rv[r][tid] && oj < rj[r][tid])) {
            rv[r][tid] = ov; rj[r][tid] = oj;
          }
        }
      }
      __syncthreads();
    }
    if (tid < nb) idx_ws[flagged[base + tid]] = rj[tid][0];
  }
}

// ---------------------------------------------------------------------------
// Kernel 5: idx (as float), age reset, usage histogram — after refine.
__global__ __launch_bounds__(256) void vq_scatter(
    const int* __restrict__ idx_ws, float* __restrict__ out) {
  int m = blockIdx.x * 256 + threadIdx.x;
  if (m >= M_TOT) return;
  int j = idx_ws[m];
  out[O_IDX + m] = (float)j;
  out[O_AGE + j] = 0.0f;            // benign race: all write 0
  atomicAdd(&out[O_USAGE + j], 1.0f);
}

// ---------------------------------------------------------------------------
// Kernel 6: z_q_st = z + (q - z) (mimics ref rounding), loss accumulation
// (one atomic per block via LDS wave-partials).
__global__ __launch_bounds__(256) void vq_gather(
    const float* __restrict__ z, const float* __restrict__ emb,
    const int* __restrict__ idx_ws, float* __restrict__ out) {
  __shared__ float lsum[4];
  size_t e4 = (size_t)blockIdx.x * 256 + threadIdx.x;  // float4 index
  size_t m = e4 >> 6;       // / (D/4)
  int dq = (int)(e4 & 63);
  int j = idx_ws[m];
  float4 q = *reinterpret_cast<const float4*>(emb + (size_t)j * D_DIM + dq * 4);
  float4 zv = *reinterpret_cast<const float4*>(z + e4 * 4);
  float dx = q.x - zv.x, dy = q.y - zv.y, dz = q.z - zv.z, dw = q.w - zv.w;
  float4 o;
  o.x = zv.x + dx; o.y = zv.y + dy; o.z = zv.z + dz; o.w = zv.w + dw;
  *reinterpret_cast<float4*>(out + e4 * 4) = o;
  float ls = dx * dx + dy * dy + dz * dz + dw * dw;
#pragma unroll
  for (int off = 32; off > 0; off >>= 1) ls += __shfl_down(ls, off, 64);
  if ((threadIdx.x & 63) == 0) lsum[threadIdx.x >> 6] = ls;
  __syncthreads();
  if (threadIdx.x == 0)
    atomicAdd(out + O_LOSS,
              (lsum[0] + lsum[1] + lsum[2] + lsum[3]) * (1.25f / 8388608.f));
}

// ---------------------------------------------------------------------------
// ws layout (f32 units): zzf[32768] | enf[8192] | idx_ws[32768] | cnt |
//   flagged[32768] | pv1[4*32768] | pv2[4*32768] | pj1[4*32768]  (~2.0 MB)
extern "C" void kernel_launch(void* const* d_in, const int* in_sizes, int n_in,
                              void* d_out, int out_size, void* d_ws, size_t ws_size,
                              hipStream_t stream) {
  const float* z = (const float*)d_in[0];
  const float* emb = (const float*)d_in[1];
  const float* code_age = (const float*)d_in[2];
  const float* code_usage = (const float*)d_in[3];
  float* out = (float*)d_out;

  float* zzf = (float*)d_ws;
  float* enf = zzf + M_TOT;
  int* idx_ws = (int*)(enf + NE);
  int* cnt = idx_ws + M_TOT;
  int* flagged = cnt + 1;
  float* pv1 = (float*)(flagged + M_TOT);
  float* pv2 = pv1 + NSPLIT * M_TOT;
  int* pj1 = (int*)(pv2 + NSPLIT * M_TOT);

  hipLaunchKernelGGL(vq_prep, dim3(M_TOT / 256), dim3(256), 0, stream,
                     z, emb, code_age, code_usage, out, zzf, enf, cnt);
  hipLaunchKernelGGL(vq_argmin_f32, dim3(M_TOT / BM, NSPLIT), dim3(256), 0, stream,
                     z, emb, zzf, enf, pv1, pv2, pj1);
  hipLaunchKernelGGL(vq_merge, dim3(M_TOT / 256), dim3(256), 0, stream,
                     pv1, pv2, pj1, idx_ws, cnt, flagged);
  hipLaunchKernelGGL(vq_refine, dim3(1024), dim3(256), 0, stream,
                     z, emb, zzf, enf, idx_ws, cnt, flagged);
  hipLaunchKernelGGL(vq_scatter, dim3(M_TOT / 256), dim3(256), 0, stream,
                     idx_ws, out);
  hipLaunchKernelGGL(vq_gather, dim3((M_TOT * (D_DIM / 4)) / 256), dim3(256), 0, stream,
                     z, emb, idx_ws, out);
}

// Round 6
// 1488.134 us; speedup vs baseline: 3.3921x; 2.0966x over previous
//
#include <hip/hip_runtime.h>
#include <math.h>

// Problem constants (z: [2,16384,256] f32, emb: [8192,256] f32)
#define D_DIM 256
#define NE    8192
#define M_TOT 32768L

// Output layout (f32 elements): z_q_st | loss | idx | age | usage
#define O_LOSS  8388608L
#define O_IDX   8388609L
#define O_AGE   8421377L
#define O_USAGE 8429569L

typedef __attribute__((ext_vector_type(8))) short bf16x8;
typedef __attribute__((ext_vector_type(4))) short bf16x4;
typedef __attribute__((ext_vector_type(4))) float f32x4;

__device__ __forceinline__ short f2bf(float f) {   // RNE f32 -> bf16 bits
  unsigned u = __float_as_uint(f);
  u += 0x7FFFu + ((u >> 16) & 1u);
  return (short)(u >> 16);
}
__device__ __forceinline__ float bf2f(short s) {
  return __uint_as_float(((unsigned)(unsigned short)s) << 16);
}

// ---------------------------------------------------------------------------
// Kernel 1: f32 row norms (f64-accumulated, f32-rounded) for z and emb,
// init age/usage defaults, zero loss + flag counter.
__global__ __launch_bounds__(256) void vq_prep(
    const float* __restrict__ z, const float* __restrict__ emb,
    const float* __restrict__ code_age, const float* __restrict__ code_usage,
    float* __restrict__ out, float* __restrict__ zzf, float* __restrict__ enf,
    int* __restrict__ cnt) {
  int t = blockIdx.x * 256 + threadIdx.x;  // 0..32767
  {
    const float4* row = reinterpret_cast<const float4*>(z + (size_t)t * D_DIM);
    double s = 0.0;
#pragma unroll
    for (int q = 0; q < D_DIM / 4; ++q) {
      float4 v = row[q];
      s = fma((double)v.x, (double)v.x, s);
      s = fma((double)v.y, (double)v.y, s);
      s = fma((double)v.z, (double)v.z, s);
      s = fma((double)v.w, (double)v.w, s);
    }
    zzf[t] = (float)s;
  }
  if (t < NE) {
    const float4* row = reinterpret_cast<const float4*>(emb + (size_t)t * D_DIM);
    double s = 0.0;
#pragma unroll
    for (int q = 0; q < D_DIM / 4; ++q) {
      float4 v = row[q];
      s = fma((double)v.x, (double)v.x, s);
      s = fma((double)v.y, (double)v.y, s);
      s = fma((double)v.z, (double)v.z, s);
      s = fma((double)v.w, (double)v.w, s);
    }
    enf[t] = (float)s;
    out[O_AGE + t] = code_age[t] + 1.0f;
    out[O_USAGE + t] = code_usage[t];
    if (t == 0) { out[O_LOSS] = 0.0f; *cnt = 0; }
  }
}

// ---------------------------------------------------------------------------
// Kernel 2: split-bf16 MFMA argmin pass.
// 256 blocks x 512 threads (8 waves: 4 row-groups x 2 col-groups).
// Block tile 128 rows x full 8192 codes (jt loop). Wave tile 32x64.
// z split (hi+lo bf16) held in registers for the whole code loop; emb slice
// split into LDS per k-step. ze = zl*eh + zh*eh + zh*el (3 MFMA, f32 acc).
// Epilogue: dv = fl(fl(zz-2*ze)+en), per-row top-2, lowest-index ties.
#define LDK 40   // shorts per LDS row (32 + 8 pad) -> 80 B stride, 2-way banks

__global__ __launch_bounds__(512, 2) void vq_argmin_mfma(
    const float* __restrict__ z, const float* __restrict__ emb,
    const float* __restrict__ zzf, const float* __restrict__ enf,
    float* __restrict__ pv1, float* __restrict__ pv2, int* __restrict__ pj1) {
  __shared__ short th[128 * LDK];
  __shared__ short tl[128 * LDK];

  const int tid = threadIdx.x;
  const int lane = tid & 63;
  const int wave = tid >> 6;        // 0..7
  const int wr = wave >> 1;         // row group 0..3
  const int wc = wave & 1;          // col group 0..1
  const int lrow = lane & 15;
  const int lq = lane >> 4;         // 0..3
  const size_t row0 = (size_t)blockIdx.x * 128;

  const int srow = tid >> 2;        // staging: 0..127
  const int skq = (tid & 3) * 8;    // staging k offset 0,8,16,24

  // ---- phase 1: split A (z rows) into register fragments, full K ----
  bf16x8 afh[2][8], afl[2][8];
#pragma unroll
  for (int ks = 0; ks < 8; ++ks) {
    __syncthreads();
    {
      const float* src = z + (row0 + srow) * (size_t)D_DIM + ks * 32 + skq;
      float4 v0 = *reinterpret_cast<const float4*>(src);
      float4 v1 = *reinterpret_cast<const float4*>(src + 4);
      float s[8] = {v0.x, v0.y, v0.z, v0.w, v1.x, v1.y, v1.z, v1.w};
      short h[8], l[8];
#pragma unroll
      for (int i = 0; i < 8; ++i) {
        h[i] = f2bf(s[i]);
        l[i] = f2bf(s[i] - bf2f(h[i]));
      }
      bf16x4 hv0 = {h[0], h[1], h[2], h[3]}, hv1 = {h[4], h[5], h[6], h[7]};
      bf16x4 lv0 = {l[0], l[1], l[2], l[3]}, lv1 = {l[4], l[5], l[6], l[7]};
      *reinterpret_cast<bf16x4*>(&th[srow * LDK + skq]) = hv0;
      *reinterpret_cast<bf16x4*>(&th[srow * LDK + skq + 4]) = hv1;
      *reinterpret_cast<bf16x4*>(&tl[srow * LDK + skq]) = lv0;
      *reinterpret_cast<bf16x4*>(&tl[srow * LDK + skq + 4]) = lv1;
    }
    __syncthreads();
#pragma unroll
    for (int rt = 0; rt < 2; ++rt) {
      int r = wr * 32 + rt * 16 + lrow;
      afh[rt][ks] = *reinterpret_cast<const bf16x8*>(&th[r * LDK + lq * 8]);
      afl[rt][ks] = *reinterpret_cast<const bf16x8*>(&tl[r * LDK + lq * 8]);
    }
  }

  // per-lane row slots: slot s=rt*4+rr -> row row0 + wr*32 + rt*16 + lq*4 + rr
  float zrow2[8];
#pragma unroll
  for (int rt = 0; rt < 2; ++rt)
#pragma unroll
    for (int rr = 0; rr < 4; ++rr)
      zrow2[rt * 4 + rr] = zzf[row0 + wr * 32 + rt * 16 + lq * 4 + rr];

  float bv1[8], bv2[8];
  int bj1[8];
#pragma unroll
  for (int s = 0; s < 8; ++s) { bv1[s] = INFINITY; bv2[s] = INFINITY; bj1[s] = 0; }

  // ---- phase 2: loop over 64 code tiles of 128 ----
  for (int jt0 = 0; jt0 < NE; jt0 += 128) {
    float enq[4];
#pragma unroll
    for (int ct = 0; ct < 4; ++ct) enq[ct] = enf[jt0 + wc * 64 + ct * 16 + lrow];

    f32x4 acc[2][4];
#pragma unroll
    for (int rt = 0; rt < 2; ++rt)
#pragma unroll
      for (int ct = 0; ct < 4; ++ct) acc[rt][ct] = (f32x4){0.f, 0.f, 0.f, 0.f};

#pragma unroll
    for (int ks = 0; ks < 8; ++ks) {
      __syncthreads();
      {
        const float* src = emb + (size_t)(jt0 + srow) * D_DIM + ks * 32 + skq;
        float4 v0 = *reinterpret_cast<const float4*>(src);
        float4 v1 = *reinterpret_cast<const float4*>(src + 4);
        float s[8] = {v0.x, v0.y, v0.z, v0.w, v1.x, v1.y, v1.z, v1.w};
        short h[8], l[8];
#pragma unroll
        for (int i = 0; i < 8; ++i) {
          h[i] = f2bf(s[i]);
          l[i] = f2bf(s[i] - bf2f(h[i]));
        }
        bf16x4 hv0 = {h[0], h[1], h[2], h[3]}, hv1 = {h[4], h[5], h[6], h[7]};
        bf16x4 lv0 = {l[0], l[1], l[2], l[3]}, lv1 = {l[4], l[5], l[6], l[7]};
        *reinterpret_cast<bf16x4*>(&th[srow * LDK + skq]) = hv0;
        *reinterpret_cast<bf16x4*>(&th[srow * LDK + skq + 4]) = hv1;
        *reinterpret_cast<bf16x4*>(&tl[srow * LDK + skq]) = lv0;
        *reinterpret_cast<bf16x4*>(&tl[srow * LDK + skq + 4]) = lv1;
      }
      __syncthreads();
      bf16x8 bf[4];
#pragma unroll
      for (int ct = 0; ct < 4; ++ct) {
        int c = wc * 64 + ct * 16 + lrow;
        bf[ct] = *reinterpret_cast<const bf16x8*>(&th[c * LDK + lq * 8]);
      }
#pragma unroll
      for (int rt = 0; rt < 2; ++rt)
#pragma unroll
        for (int ct = 0; ct < 4; ++ct) {
          acc[rt][ct] = __builtin_amdgcn_mfma_f32_16x16x32_bf16(
              afl[rt][ks], bf[ct], acc[rt][ct], 0, 0, 0);   // zl*eh
          acc[rt][ct] = __builtin_amdgcn_mfma_f32_16x16x32_bf16(
              afh[rt][ks], bf[ct], acc[rt][ct], 0, 0, 0);   // zh*eh
        }
#pragma unroll
      for (int ct = 0; ct < 4; ++ct) {
        int c = wc * 64 + ct * 16 + lrow;
        bf[ct] = *reinterpret_cast<const bf16x8*>(&tl[c * LDK + lq * 8]);
      }
#pragma unroll
      for (int rt = 0; rt < 2; ++rt)
#pragma unroll
        for (int ct = 0; ct < 4; ++ct)
          acc[rt][ct] = __builtin_amdgcn_mfma_f32_16x16x32_bf16(
              afh[rt][ks], bf[ct], acc[rt][ct], 0, 0, 0);   // zh*el
    }

    // epilogue: reference f32 chain; ct ascending + jt ascending + strict <
    // -> lowest index on ties
#pragma unroll
    for (int ct = 0; ct < 4; ++ct) {
      int gj = jt0 + wc * 64 + ct * 16 + lrow;
      float ef = enq[ct];
#pragma unroll
      for (int rt = 0; rt < 2; ++rt)
#pragma unroll
        for (int rr = 0; rr < 4; ++rr) {
          int s = rt * 4 + rr;
          float t = zrow2[s] - 2.0f * acc[rt][ct][rr];
          float dv = t + ef;
          if (dv < bv1[s]) {
            bv2[s] = bv1[s]; bv1[s] = dv; bj1[s] = gj;
          } else if (dv < bv2[s]) {
            bv2[s] = dv;
          }
        }
    }
  }

  // reduce top-2 across the 16 code-lanes (lrow) of each lane quarter
#pragma unroll
  for (int m = 1; m < 16; m <<= 1) {
#pragma unroll
    for (int s = 0; s < 8; ++s) {
      float ov1 = __shfl_xor(bv1[s], m, 16);
      float ov2 = __shfl_xor(bv2[s], m, 16);
      int oj1 = __shfl_xor(bj1[s], m, 16);
      if (ov1 < bv1[s] || (ov1 == bv1[s] && oj1 < bj1[s])) {
        bv2[s] = fminf(bv1[s], ov2);
        bv1[s] = ov1; bj1[s] = oj1;
      } else {
        bv2[s] = fminf(bv2[s], ov1);
      }
    }
  }
  if (lrow == 0) {
#pragma unroll
    for (int s = 0; s < 8; ++s) {
      size_t grow = row0 + wr * 32 + (s >> 2) * 16 + lq * 4 + (s & 3);
      size_t o = (size_t)wc * M_TOT + grow;
      pv1[o] = bv1[s]; pv2[o] = bv2[s]; pj1[o] = bj1[s];
    }
  }
}

// ---------------------------------------------------------------------------
// Kernel 3: fold the 2 col-split partial top-2s per row; flag ambiguous rows.
// Margin: 2*ulp(dv grid) covers ours-vs-ref quantization; 1e-5 slack covers
// worst-coherent split-bf16 ze error (<=4.2e-6 in dv) with 2x headroom.
#define MSPLIT 2

__global__ __launch_bounds__(256) void vq_merge(
    const float* __restrict__ pv1, const float* __restrict__ pv2,
    const int* __restrict__ pj1, int* __restrict__ idx_ws,
    int* __restrict__ cnt, int* __restrict__ flagged) {
  int m = blockIdx.x * 256 + threadIdx.x;
  if (m >= M_TOT) return;
  float v1 = INFINITY, v2 = INFINITY;
  int j1 = 0;
#pragma unroll
  for (int s = 0; s < MSPLIT; ++s) {
    float a1 = pv1[(size_t)s * M_TOT + m];
    float a2 = pv2[(size_t)s * M_TOT + m];
    int aj = pj1[(size_t)s * M_TOT + m];
    if (a1 < v1 || (a1 == v1 && aj < j1)) {
      v2 = fminf(v1, a2); v1 = a1; j1 = aj;
    } else {
      v2 = fminf(v2, a1);
    }
  }
  idx_ws[m] = j1;
  float u = ldexpf(1.0f, ilogbf(v2) - 23);
  if (v2 - v1 <= 2.0f * u + 1e-5f) {
    int p = atomicAdd(cnt, 1);
    flagged[p] = m;
  }
}

// ---------------------------------------------------------------------------
// Kernel 4: exact refine for flagged rows. 4 rows/block, full 8192-code scan,
// f64 dot (correctly-rounded f32 ze), reference f32 chain, lowest-index ties.
#define RROWS 4

__global__ __launch_bounds__(256) void vq_refine(
    const float* __restrict__ z, const float* __restrict__ emb,
    const float* __restrict__ zzf, const float* __restrict__ enf,
    int* __restrict__ idx_ws, const int* __restrict__ cnt,
    const int* __restrict__ flagged) {
  __shared__ float zs[RROWS][D_DIM + 4];
  __shared__ float rzz[RROWS];
  __shared__ float rv[RROWS][256];
  __shared__ int rj[RROWS][256];

  const int tid = threadIdx.x;
  int n = *cnt;
  if (n > (int)M_TOT) n = (int)M_TOT;

  for (int base = blockIdx.x * RROWS; base < n; base += gridDim.x * RROWS) {
    int nb = n - base; if (nb > RROWS) nb = RROWS;
    __syncthreads();
    {
      int r = tid >> 6;               // 4 rows x 64 threads
      int kk = (tid & 63) * 4;        // one float4 each
      if (r < nb) {
        size_t m = (size_t)flagged[base + r];
        *reinterpret_cast<float4*>(&zs[r][kk]) =
            *reinterpret_cast<const float4*>(z + m * D_DIM + kk);
      }
      if (tid < nb) rzz[tid] = zzf[flagged[base + tid]];
    }
    __syncthreads();

    float bv[RROWS]; int bj[RROWS];
#pragma unroll
    for (int r = 0; r < RROWS; ++r) { bv[r] = INFINITY; bj[r] = 0; }

    for (int j = tid; j < NE; j += 256) {
      const float4* er = reinterpret_cast<const float4*>(emb + (size_t)j * D_DIM);
      double acc[RROWS];
#pragma unroll
      for (int r = 0; r < RROWS; ++r) acc[r] = 0.0;
      for (int k4 = 0; k4 < D_DIM / 4; ++k4) {
        float4 ev = er[k4];
        double e0 = ev.x, e1 = ev.y, e2 = ev.z, e3 = ev.w;
#pragma unroll
        for (int r = 0; r < RROWS; ++r) {
          float4 zv = *reinterpret_cast<const float4*>(&zs[r][k4 * 4]);
          double a = acc[r];
          a = fma((double)zv.x, e0, a);
          a = fma((double)zv.y, e1, a);
          a = fma((double)zv.z, e2, a);
          a = fma((double)zv.w, e3, a);
          acc[r] = a;
        }
      }
      float ef = enf[j];
#pragma unroll
      for (int r = 0; r < RROWS; ++r) {
        float zef = (float)acc[r];          // correctly-rounded f32(ze)
        float t = rzz[r] - 2.0f * zef;
        float dv = t + ef;
        if (dv < bv[r]) { bv[r] = dv; bj[r] = j; }   // j ascending
      }
    }
#pragma unroll
    for (int r = 0; r < RROWS; ++r) { rv[r][tid] = bv[r]; rj[r][tid] = bj[r]; }
    __syncthreads();
    for (int s = 128; s > 0; s >>= 1) {
      if (tid < s) {
#pragma unroll
        for (int r = 0; r < RROWS; ++r) {
          float ov = rv[r][tid + s]; int oj = rj[r][tid + s];
          if (ov < rv[r][tid] || (ov == rv[r][tid] && oj < rj[r][tid])) {
            rv[r][tid] = ov; rj[r][tid] = oj;
          }
        }
      }
      __syncthreads();
    }
    if (tid < nb) idx_ws[flagged[base + tid]] = rj[tid][0];
  }
}

// ---------------------------------------------------------------------------
// Kernel 5: idx (as float), age reset, usage histogram — after refine.
__global__ __launch_bounds__(256) void vq_scatter(
    const int* __restrict__ idx_ws, float* __restrict__ out) {
  int m = blockIdx.x * 256 + threadIdx.x;
  if (m >= M_TOT) return;
  int j = idx_ws[m];
  out[O_IDX + m] = (float)j;
  out[O_AGE + j] = 0.0f;            // benign race: all write 0
  atomicAdd(&out[O_USAGE + j], 1.0f);
}

// ---------------------------------------------------------------------------
// Kernel 6: z_q_st = z + (q - z) (mimics ref rounding), loss accumulation
// (one atomic per block via LDS wave-partials).
__global__ __launch_bounds__(256) void vq_gather(
    const float* __restrict__ z, const float* __restrict__ emb,
    const int* __restrict__ idx_ws, float* __restrict__ out) {
  __shared__ float lsum[4];
  size_t e4 = (size_t)blockIdx.x * 256 + threadIdx.x;  // float4 index
  size_t m = e4 >> 6;       // / (D/4)
  int dq = (int)(e4 & 63);
  int j = idx_ws[m];
  float4 q = *reinterpret_cast<const float4*>(emb + (size_t)j * D_DIM + dq * 4);
  float4 zv = *reinterpret_cast<const float4*>(z + e4 * 4);
  float dx = q.x - zv.x, dy = q.y - zv.y, dz = q.z - zv.z, dw = q.w - zv.w;
  float4 o;
  o.x = zv.x + dx; o.y = zv.y + dy; o.z = zv.z + dz; o.w = zv.w + dw;
  *reinterpret_cast<float4*>(out + e4 * 4) = o;
  float ls = dx * dx + dy * dy + dz * dz + dw * dw;
#pragma unroll
  for (int off = 32; off > 0; off >>= 1) ls += __shfl_down(ls, off, 64);
  if ((threadIdx.x & 63) == 0) lsum[threadIdx.x >> 6] = ls;
  __syncthreads();
  if (threadIdx.x == 0)
    atomicAdd(out + O_LOSS,
              (lsum[0] + lsum[1] + lsum[2] + lsum[3]) * (1.25f / 8388608.f));
}

// ---------------------------------------------------------------------------
// ws layout (f32 units): zzf[32768] | enf[8192] | idx_ws[32768] | cnt |
//   flagged[32768] | pv1[2*32768] | pv2[2*32768] | pj1[2*32768]  (~1.2 MB)
extern "C" void kernel_launch(void* const* d_in, const int* in_sizes, int n_in,
                              void* d_out, int out_size, void* d_ws, size_t ws_size,
                              hipStream_t stream) {
  const float* z = (const float*)d_in[0];
  const float* emb = (const float*)d_in[1];
  const float* code_age = (const float*)d_in[2];
  const float* code_usage = (const float*)d_in[3];
  float* out = (float*)d_out;

  float* zzf = (float*)d_ws;
  float* enf = zzf + M_TOT;
  int* idx_ws = (int*)(enf + NE);
  int* cnt = idx_ws + M_TOT;
  int* flagged = cnt + 1;
  float* pv1 = (float*)(flagged + M_TOT);
  float* pv2 = pv1 + MSPLIT * M_TOT;
  int* pj1 = (int*)(pv2 + MSPLIT * M_TOT);

  hipLaunchKernelGGL(vq_prep, dim3(M_TOT / 256), dim3(256), 0, stream,
                     z, emb, code_age, code_usage, out, zzf, enf, cnt);
  hipLaunchKernelGGL(vq_argmin_mfma, dim3(M_TOT / 128), dim3(512), 0, stream,
                     z, emb, zzf, enf, pv1, pv2, pj1);
  hipLaunchKernelGGL(vq_merge, dim3(M_TOT / 256), dim3(256), 0, stream,
                     pv1, pv2, pj1, idx_ws, cnt, flagged);
  hipLaunchKernelGGL(vq_refine, dim3(2048), dim3(256), 0, stream,
                     z, emb, zzf, enf, idx_ws, cnt, flagged);
  hipLaunchKernelGGL(vq_scatter, dim3(M_TOT / 256), dim3(256), 0, stream,
                     idx_ws, out);
  hipLaunchKernelGGL(vq_gather, dim3((M_TOT * (D_DIM / 4)) / 256), dim3(256), 0, stream,
                     z, emb, idx_ws, out);
}

// Round 7
// 1486.121 us; speedup vs baseline: 3.3967x; 1.0014x over previous
//
#include <hip/hip_runtime.h>
#include <math.h>

// Problem constants (z: [2,16384,256] f32, emb: [8192,256] f32)
#define D_DIM 256
#define NE    8192
#define M_TOT 32768L

// Output layout (f32 elements): z_q_st | loss | idx | age | usage
#define O_LOSS  8388608L
#define O_IDX   8388609L
#define O_AGE   8421377L
#define O_USAGE 8429569L

typedef __attribute__((ext_vector_type(8))) short bf16x8;
typedef __attribute__((ext_vector_type(4))) short bf16x4;
typedef __attribute__((ext_vector_type(4))) float f32x4;

__device__ __forceinline__ short f2bf(float f) {   // RNE f32 -> bf16 bits
  unsigned u = __float_as_uint(f);
  u += 0x7FFFu + ((u >> 16) & 1u);
  return (short)(u >> 16);
}
__device__ __forceinline__ float bf2f(short s) {
  return __uint_as_float(((unsigned)(unsigned short)s) << 16);
}

// ---------------------------------------------------------------------------
// Kernel 1: f32 row norms (f64-accumulated, f32-rounded) for z and emb,
// init age/usage defaults, zero loss + flag counter.
__global__ __launch_bounds__(256) void vq_prep(
    const float* __restrict__ z, const float* __restrict__ emb,
    const float* __restrict__ code_age, const float* __restrict__ code_usage,
    float* __restrict__ out, float* __restrict__ zzf, float* __restrict__ enf,
    int* __restrict__ cnt) {
  int t = blockIdx.x * 256 + threadIdx.x;  // 0..32767
  {
    const float4* row = reinterpret_cast<const float4*>(z + (size_t)t * D_DIM);
    double s = 0.0;
#pragma unroll
    for (int q = 0; q < D_DIM / 4; ++q) {
      float4 v = row[q];
      s = fma((double)v.x, (double)v.x, s);
      s = fma((double)v.y, (double)v.y, s);
      s = fma((double)v.z, (double)v.z, s);
      s = fma((double)v.w, (double)v.w, s);
    }
    zzf[t] = (float)s;
  }
  if (t < NE) {
    const float4* row = reinterpret_cast<const float4*>(emb + (size_t)t * D_DIM);
    double s = 0.0;
#pragma unroll
    for (int q = 0; q < D_DIM / 4; ++q) {
      float4 v = row[q];
      s = fma((double)v.x, (double)v.x, s);
      s = fma((double)v.y, (double)v.y, s);
      s = fma((double)v.z, (double)v.z, s);
      s = fma((double)v.w, (double)v.w, s);
    }
    enf[t] = (float)s;
    out[O_AGE + t] = code_age[t] + 1.0f;
    out[O_USAGE + t] = code_usage[t];
    if (t == 0) { out[O_LOSS] = 0.0f; *cnt = 0; }
  }
}

// ---------------------------------------------------------------------------
// Kernel 2: split-bf16 MFMA argmin pass.
// 256 blocks x 512 threads (8 waves: 4 row-groups x 2 col-groups).
// Block tile 128 rows x full 8192 codes (jt loop). Wave tile 32x64.
// z split (hi+lo bf16) held in registers for the whole code loop; emb slice
// split into LDS per k-step. ze = zl*eh + zh*eh + zh*el (3 MFMA, f32 acc).
// Epilogue: dv = fl(fl(zz-2*ze)+en), per-row top-2, lowest-index ties.
#define LDK 40   // shorts per LDS row (32 + 8 pad) -> 80 B stride, 2-way banks

__global__ __launch_bounds__(512, 2) void vq_argmin_mfma(
    const float* __restrict__ z, const float* __restrict__ emb,
    const float* __restrict__ zzf, const float* __restrict__ enf,
    float* __restrict__ pv1, float* __restrict__ pv2, int* __restrict__ pj1) {
  __shared__ short th[128 * LDK];
  __shared__ short tl[128 * LDK];

  const int tid = threadIdx.x;
  const int lane = tid & 63;
  const int wave = tid >> 6;        // 0..7
  const int wr = wave >> 1;         // row group 0..3
  const int wc = wave & 1;          // col group 0..1
  const int lrow = lane & 15;
  const int lq = lane >> 4;         // 0..3
  const size_t row0 = (size_t)blockIdx.x * 128;

  const int srow = tid >> 2;        // staging: 0..127
  const int skq = (tid & 3) * 8;    // staging k offset 0,8,16,24

  // ---- phase 1: split A (z rows) into register fragments, full K ----
  bf16x8 afh[2][8], afl[2][8];
#pragma unroll
  for (int ks = 0; ks < 8; ++ks) {
    __syncthreads();
    {
      const float* src = z + (row0 + srow) * (size_t)D_DIM + ks * 32 + skq;
      float4 v0 = *reinterpret_cast<const float4*>(src);
      float4 v1 = *reinterpret_cast<const float4*>(src + 4);
      float s[8] = {v0.x, v0.y, v0.z, v0.w, v1.x, v1.y, v1.z, v1.w};
      short h[8], l[8];
#pragma unroll
      for (int i = 0; i < 8; ++i) {
        h[i] = f2bf(s[i]);
        l[i] = f2bf(s[i] - bf2f(h[i]));
      }
      bf16x4 hv0 = {h[0], h[1], h[2], h[3]}, hv1 = {h[4], h[5], h[6], h[7]};
      bf16x4 lv0 = {l[0], l[1], l[2], l[3]}, lv1 = {l[4], l[5], l[6], l[7]};
      *reinterpret_cast<bf16x4*>(&th[srow * LDK + skq]) = hv0;
      *reinterpret_cast<bf16x4*>(&th[srow * LDK + skq + 4]) = hv1;
      *reinterpret_cast<bf16x4*>(&tl[srow * LDK + skq]) = lv0;
      *reinterpret_cast<bf16x4*>(&tl[srow * LDK + skq + 4]) = lv1;
    }
    __syncthreads();
#pragma unroll
    for (int rt = 0; rt < 2; ++rt) {
      int r = wr * 32 + rt * 16 + lrow;
      afh[rt][ks] = *reinterpret_cast<const bf16x8*>(&th[r * LDK + lq * 8]);
      afl[rt][ks] = *reinterpret_cast<const bf16x8*>(&tl[r * LDK + lq * 8]);
    }
  }

  // per-lane row slots: slot s=rt*4+rr -> row row0 + wr*32 + rt*16 + lq*4 + rr
  float zrow2[8];
#pragma unroll
  for (int rt = 0; rt < 2; ++rt)
#pragma unroll
    for (int rr = 0; rr < 4; ++rr)
      zrow2[rt * 4 + rr] = zzf[row0 + wr * 32 + rt * 16 + lq * 4 + rr];

  float bv1[8], bv2[8];
  int bj1[8];
#pragma unroll
  for (int s = 0; s < 8; ++s) { bv1[s] = INFINITY; bv2[s] = INFINITY; bj1[s] = 0; }

  // ---- phase 2: loop over 64 code tiles of 128 ----
  for (int jt0 = 0; jt0 < NE; jt0 += 128) {
    float enq[4];
#pragma unroll
    for (int ct = 0; ct < 4; ++ct) enq[ct] = enf[jt0 + wc * 64 + ct * 16 + lrow];

    f32x4 acc[2][4];
#pragma unroll
    for (int rt = 0; rt < 2; ++rt)
#pragma unroll
      for (int ct = 0; ct < 4; ++ct) acc[rt][ct] = (f32x4){0.f, 0.f, 0.f, 0.f};

#pragma unroll
    for (int ks = 0; ks < 8; ++ks) {
      __syncthreads();
      {
        const float* src = emb + (size_t)(jt0 + srow) * D_DIM + ks * 32 + skq;
        float4 v0 = *reinterpret_cast<const float4*>(src);
        float4 v1 = *reinterpret_cast<const float4*>(src + 4);
        float s[8] = {v0.x, v0.y, v0.z, v0.w, v1.x, v1.y, v1.z, v1.w};
        short h[8], l[8];
#pragma unroll
        for (int i = 0; i < 8; ++i) {
          h[i] = f2bf(s[i]);
          l[i] = f2bf(s[i] - bf2f(h[i]));
        }
        bf16x4 hv0 = {h[0], h[1], h[2], h[3]}, hv1 = {h[4], h[5], h[6], h[7]};
        bf16x4 lv0 = {l[0], l[1], l[2], l[3]}, lv1 = {l[4], l[5], l[6], l[7]};
        *reinterpret_cast<bf16x4*>(&th[srow * LDK + skq]) = hv0;
        *reinterpret_cast<bf16x4*>(&th[srow * LDK + skq + 4]) = hv1;
        *reinterpret_cast<bf16x4*>(&tl[srow * LDK + skq]) = lv0;
        *reinterpret_cast<bf16x4*>(&tl[srow * LDK + skq + 4]) = lv1;
      }
      __syncthreads();
      bf16x8 bf[4];
#pragma unroll
      for (int ct = 0; ct < 4; ++ct) {
        int c = wc * 64 + ct * 16 + lrow;
        bf[ct] = *reinterpret_cast<const bf16x8*>(&th[c * LDK + lq * 8]);
      }
#pragma unroll
      for (int rt = 0; rt < 2; ++rt)
#pragma unroll
        for (int ct = 0; ct < 4; ++ct) {
          acc[rt][ct] = __builtin_amdgcn_mfma_f32_16x16x32_bf16(
              afl[rt][ks], bf[ct], acc[rt][ct], 0, 0, 0);   // zl*eh
          acc[rt][ct] = __builtin_amdgcn_mfma_f32_16x16x32_bf16(
              afh[rt][ks], bf[ct], acc[rt][ct], 0, 0, 0);   // zh*eh
        }
#pragma unroll
      for (int ct = 0; ct < 4; ++ct) {
        int c = wc * 64 + ct * 16 + lrow;
        bf[ct] = *reinterpret_cast<const bf16x8*>(&tl[c * LDK + lq * 8]);
      }
#pragma unroll
      for (int rt = 0; rt < 2; ++rt)
#pragma unroll
        for (int ct = 0; ct < 4; ++ct)
          acc[rt][ct] = __builtin_amdgcn_mfma_f32_16x16x32_bf16(
              afh[rt][ks], bf[ct], acc[rt][ct], 0, 0, 0);   // zh*el
    }

    // epilogue: reference f32 chain; ct ascending + jt ascending + strict <
    // -> lowest index on ties
#pragma unroll
    for (int ct = 0; ct < 4; ++ct) {
      int gj = jt0 + wc * 64 + ct * 16 + lrow;
      float ef = enq[ct];
#pragma unroll
      for (int rt = 0; rt < 2; ++rt)
#pragma unroll
        for (int rr = 0; rr < 4; ++rr) {
          int s = rt * 4 + rr;
          float t = zrow2[s] - 2.0f * acc[rt][ct][rr];
          float dv = t + ef;
          if (dv < bv1[s]) {
            bv2[s] = bv1[s]; bv1[s] = dv; bj1[s] = gj;
          } else if (dv < bv2[s]) {
            bv2[s] = dv;
          }
        }
    }
  }

  // reduce top-2 across the 16 code-lanes (lrow) of each lane quarter
#pragma unroll
  for (int m = 1; m < 16; m <<= 1) {
#pragma unroll
    for (int s = 0; s < 8; ++s) {
      float ov1 = __shfl_xor(bv1[s], m, 16);
      float ov2 = __shfl_xor(bv2[s], m, 16);
      int oj1 = __shfl_xor(bj1[s], m, 16);
      if (ov1 < bv1[s] || (ov1 == bv1[s] && oj1 < bj1[s])) {
        bv2[s] = fminf(bv1[s], ov2);
        bv1[s] = ov1; bj1[s] = oj1;
      } else {
        bv2[s] = fminf(bv2[s], ov1);
      }
    }
  }
  if (lrow == 0) {
#pragma unroll
    for (int s = 0; s < 8; ++s) {
      size_t grow = row0 + wr * 32 + (s >> 2) * 16 + lq * 4 + (s & 3);
      size_t o = (size_t)wc * M_TOT + grow;
      pv1[o] = bv1[s]; pv2[o] = bv2[s]; pj1[o] = bj1[s];
    }
  }
}

// ---------------------------------------------------------------------------
// Kernel 3: fold the 2 col-split partial top-2s per row; flag ambiguous rows.
// Margin: 2*ulp(dv grid) covers ours-vs-ref quantization; 1e-5 slack covers
// worst-coherent split-bf16 ze error (<=4.2e-6 in dv) with 2x headroom.
#define MSPLIT 2

__global__ __launch_bounds__(256) void vq_merge(
    const float* __restrict__ pv1, const float* __restrict__ pv2,
    const int* __restrict__ pj1, int* __restrict__ idx_ws,
    int* __restrict__ cnt, int* __restrict__ flagged) {
  int m = blockIdx.x * 256 + threadIdx.x;
  if (m >= M_TOT) return;
  float v1 = INFINITY, v2 = INFINITY;
  int j1 = 0;
#pragma unroll
  for (int s = 0; s < MSPLIT; ++s) {
    float a1 = pv1[(size_t)s * M_TOT + m];
    float a2 = pv2[(size_t)s * M_TOT + m];
    int aj = pj1[(size_t)s * M_TOT + m];
    if (a1 < v1 || (a1 == v1 && aj < j1)) {
      v2 = fminf(v1, a2); v1 = a1; j1 = aj;
    } else {
      v2 = fminf(v2, a1);
    }
  }
  idx_ws[m] = j1;
  float u = ldexpf(1.0f, ilogbf(v2) - 23);
  if (v2 - v1 <= 2.0f * u + 1e-5f) {
    int p = atomicAdd(cnt, 1);
    flagged[p] = m;
  }
}

// ---------------------------------------------------------------------------
// Kernel 4: exact refine for flagged rows. 4 rows/block, full 8192-code scan,
// f64 dot (correctly-rounded f32 ze), reference f32 chain, lowest-index ties.
#define RROWS 4

__global__ __launch_bounds__(256) void vq_refine(
    const float* __restrict__ z, const float* __restrict__ emb,
    const float* __restrict__ zzf, const float* __restrict__ enf,
    int* __restrict__ idx_ws, const int* __restrict__ cnt,
    const int* __restrict__ flagged) {
  __shared__ float zs[RROWS][D_DIM + 4];
  __shared__ float rzz[RROWS];
  __shared__ float rv[RROWS][256];
  __shared__ int rj[RROWS][256];

  const int tid = threadIdx.x;
  int n = *cnt;
  if (n > (int)M_TOT) n = (int)M_TOT;

  for (int base = blockIdx.x * RROWS; base < n; base += gridDim.x * RROWS) {
    int nb = n - base; if (nb > RROWS) nb = RROWS;
    __syncthreads();
    {
      int r = tid >> 6;               // 4 rows x 64 threads
      int kk = (tid & 63) * 4;        // one float4 each
      if (r < nb) {
        size_t m = (size_t)flagged[base + r];
        *reinterpret_cast<float4*>(&zs[r][kk]) =
            *reinterpret_cast<const float4*>(z + m * D_DIM + kk);
      }
      if (tid < nb) rzz[tid] = zzf[flagged[base + tid]];
    }
    __syncthreads();

    float bv[RROWS]; int bj[RROWS];
#pragma unroll
    for (int r = 0; r < RROWS; ++r) { bv[r] = INFINITY; bj[r] = 0; }

    for (int j = tid; j < NE; j += 256) {
      const float4* er = reinterpret_cast<const float4*>(emb + (size_t)j * D_DIM);
      double acc[RROWS];
#pragma unroll
      for (int r = 0; r < RROWS; ++r) acc[r] = 0.0;
      for (int k4 = 0; k4 < D_DIM / 4; ++k4) {
        float4 ev = er[k4];
        double e0 = ev.x, e1 = ev.y, e2 = ev.z, e3 = ev.w;
#pragma unroll
        for (int r = 0; r < RROWS; ++r) {
          float4 zv = *reinterpret_cast<const float4*>(&zs[r][k4 * 4]);
          double a = acc[r];
          a = fma((double)zv.x, e0, a);
          a = fma((double)zv.y, e1, a);
          a = fma((double)zv.z, e2, a);
          a = fma((double)zv.w, e3, a);
          acc[r] = a;
        }
      }
      float ef = enf[j];
#pragma unroll
      for (int r = 0; r < RROWS; ++r) {
        float zef = (float)acc[r];          // correctly-rounded f32(ze)
        float t = rzz[r] - 2.0f * zef;
        float dv = t + ef;
        if (dv < bv[r]) { bv[r] = dv; bj[r] = j; }   // j ascending
      }
    }
#pragma unroll
    for (int r = 0; r < RROWS; ++r) { rv[r][tid] = bv[r]; rj[r][tid] = bj[r]; }
    __syncthreads();
    for (int s = 128; s > 0; s >>= 1) {
      if (tid < s) {
#pragma unroll
        for (int r = 0; r < RROWS; ++r) {
          float ov = rv[r][tid + s]; int oj = rj[r][tid + s];
          if (ov < rv[r][tid] || (ov == rv[r][tid] && oj < rj[r][tid])) {
            rv[r][tid] = ov; rj[r][tid] = oj;
          }
        }
      }
      __syncthreads();
    }
    if (tid < nb) idx_ws[flagged[base + tid]] = rj[tid][0];
  }
}

// ---------------------------------------------------------------------------
// Kernel 5: idx (as float), age reset, usage histogram — after refine.
__global__ __launch_bounds__(256) void vq_scatter(
    const int* __restrict__ idx_ws, float* __restrict__ out) {
  int m = blockIdx.x * 256 + threadIdx.x;
  if (m >= M_TOT) return;
  int j = idx_ws[m];
  out[O_IDX + m] = (float)j;
  out[O_AGE + j] = 0.0f;            // benign race: all write 0
  atomicAdd(&out[O_USAGE + j], 1.0f);
}

// ---------------------------------------------------------------------------
// Kernel 6: z_q_st = z + (q - z) (mimics ref rounding), loss accumulation
// (one atomic per block via LDS wave-partials).
__global__ __launch_bounds__(256) void vq_gather(
    const float* __restrict__ z, const float* __restrict__ emb,
    const int* __restrict__ idx_ws, float* __restrict__ out) {
  __shared__ float lsum[4];
  size_t e4 = (size_t)blockIdx.x * 256 + threadIdx.x;  // float4 index
  size_t m = e4 >> 6;       // / (D/4)
  int dq = (int)(e4 & 63);
  int j = idx_ws[m];
  float4 q = *reinterpret_cast<const float4*>(emb + (size_t)j * D_DIM + dq * 4);
  float4 zv = *reinterpret_cast<const float4*>(z + e4 * 4);
  float dx = q.x - zv.x, dy = q.y - zv.y, dz = q.z - zv.z, dw = q.w - zv.w;
  float4 o;
  o.x = zv.x + dx; o.y = zv.y + dy; o.z = zv.z + dz; o.w = zv.w + dw;
  *reinterpret_cast<float4*>(out + e4 * 4) = o;
  float ls = dx * dx + dy * dy + dz * dz + dw * dw;
#pragma unroll
  for (int off = 32; off > 0; off >>= 1) ls += __shfl_down(ls, off, 64);
  if ((threadIdx.x & 63) == 0) lsum[threadIdx.x >> 6] = ls;
  __syncthreads();
  if (threadIdx.x == 0)
    atomicAdd(out + O_LOSS,
              (lsum[0] + lsum[1] + lsum[2] + lsum[3]) * (1.25f / 8388608.f));
}

// ---------------------------------------------------------------------------
// ws layout (f32 units): zzf[32768] | enf[8192] | idx_ws[32768] | cnt |
//   flagged[32768] | pv1[2*32768] | pv2[2*32768] | pj1[2*32768]  (~1.2 MB)
extern "C" void kernel_launch(void* const* d_in, const int* in_sizes, int n_in,
                              void* d_out, int out_size, void* d_ws, size_t ws_size,
                              hipStream_t stream) {
  const float* z = (const float*)d_in[0];
  const float* emb = (const float*)d_in[1];
  const float* code_age = (const float*)d_in[2];
  const float* code_usage = (const float*)d_in[3];
  float* out = (float*)d_out;

  float* zzf = (float*)d_ws;
  float* enf = zzf + M_TOT;
  int* idx_ws = (int*)(enf + NE);
  int* cnt = idx_ws + M_TOT;
  int* flagged = cnt + 1;
  float* pv1 = (float*)(flagged + M_TOT);
  float* pv2 = pv1 + MSPLIT * M_TOT;
  int* pj1 = (int*)(pv2 + MSPLIT * M_TOT);

  hipLaunchKernelGGL(vq_prep, dim3(M_TOT / 256), dim3(256), 0, stream,
                     z, emb, code_age, code_usage, out, zzf, enf, cnt);
  hipLaunchKernelGGL(vq_argmin_mfma, dim3(M_TOT / 128), dim3(512), 0, stream,
                     z, emb, zzf, enf, pv1, pv2, pj1);
  hipLaunchKernelGGL(vq_merge, dim3(M_TOT / 256), dim3(256), 0, stream,
                     pv1, pv2, pj1, idx_ws, cnt, flagged);
  hipLaunchKernelGGL(vq_refine, dim3(2048), dim3(256), 0, stream,
                     z, emb, zzf, enf, idx_ws, cnt, flagged);
  hipLaunchKernelGGL(vq_scatter, dim3(M_TOT / 256), dim3(256), 0, stream,
                     idx_ws, out);
  hipLaunchKernelGGL(vq_gather, dim3((M_TOT * (D_DIM / 4)) / 256), dim3(256), 0, stream,
                     z, emb, idx_ws, out);
}